// Round 9
// baseline (126.495 us; speedup 1.0000x reference)
//
#include <hip/hip_runtime.h>

using f16   = _Float16;
using f16x4 = __attribute__((ext_vector_type(4))) _Float16;
using f16x8 = __attribute__((ext_vector_type(8))) _Float16;
using f32x4 = __attribute__((ext_vector_type(4))) float;

#define BDIM 4
#define EDIM 512
#define LDIM 512
#define VDIM 32000
#define RDIM 2048            // B*L
#define INV_TAU 0.1f

using gcvoid = const __attribute__((address_space(1))) void;
using lvoid  = __attribute__((address_space(3))) void;

__device__ __forceinline__ void gload_lds16(const void* g, void* l) {
  __builtin_amdgcn_global_load_lds((gcvoid*)g, (lvoid*)l, 16, 0, 0);
}

// ---------------- kernel 1: DE [B,E,L] f32 -> A16 [R=B*L][E] f16 (transpose+convert)
__global__ void cvtA_kernel(const float* __restrict__ DE, f16* __restrict__ A16) {
  __shared__ float tile[64][65];
  const int b  = blockIdx.z;
  const int e0 = blockIdx.y * 64;
  const int l0 = blockIdx.x * 64;
  const int t  = threadIdx.x;
#pragma unroll
  for (int i = 0; i < 4; ++i) {
    int idx = t + i * 256;
    int el  = idx >> 4;
    int l4  = (idx & 15) * 4;
    float4 v = *reinterpret_cast<const float4*>(
        DE + (size_t)(b * 512 + e0 + el) * 512 + l0 + l4);
    tile[el][l4 + 0] = v.x;
    tile[el][l4 + 1] = v.y;
    tile[el][l4 + 2] = v.z;
    tile[el][l4 + 3] = v.w;
  }
  __syncthreads();
#pragma unroll
  for (int i = 0; i < 4; ++i) {
    int idx = t + i * 256;
    int ll  = idx >> 4;
    int e4  = (idx & 15) * 4;
    f16x4 h;
    h[0] = (f16)tile[e4 + 0][ll];
    h[1] = (f16)tile[e4 + 1][ll];
    h[2] = (f16)tile[e4 + 2][ll];
    h[3] = (f16)tile[e4 + 3][ll];
    *reinterpret_cast<f16x4*>(A16 + (size_t)(b * 512 + l0 + ll) * 512 + e0 + e4) = h;
  }
}

// ---------------- kernel 2: M [V,E] f32 -> B16 [V][E] f16 (stream convert)
__global__ void cvtM_kernel(const float* __restrict__ M, f16* __restrict__ B16) {
  const size_t N4 = (size_t)VDIM * EDIM / 4;
  const size_t stride = (size_t)gridDim.x * blockDim.x;
  for (size_t i = (size_t)blockIdx.x * blockDim.x + threadIdx.x; i < N4; i += stride) {
    float4 v = reinterpret_cast<const float4*>(M)[i];
    f16x4 h = { (f16)v.x, (f16)v.y, (f16)v.z, (f16)v.w };
    reinterpret_cast<f16x4*>(B16)[i] = h;
  }
}

// ---------------- kernel 3: fused GEMM + exp + vocab-sum
// R8 structure + FRAGMENT PREFETCH: ds_read of step t+1 issued during step t
// into the alternate register set, so the pre-MFMA lgkmcnt(0) waits on reads
// issued ~600 cyc earlier (removes ds_read issue+latency from the lockstep
// critical path). Ring-4 LDS (4 x 16KB = 64KB, 2 blk/CU): prefetch-read slot
// (t+1)%4 is 2 slots from staging target (t+3)%4.
// Wait ledger (re-derived): prologue stages K0..K2, vmcnt(4) proves K0,K1.
// Steady boundary: in-flight = K(t+2)+K(t+3) -> vmcnt(4) proves K(t+2),
// exactly what prefetch during t+1 needs. vmcnt(0) only at t=13 (proves K15
// for prefetch during t=14). Boundary lgkmcnt DROPPED: the WAR on slot
// (t-1)%4 (rewritten by stage during t) is closed by its readers' pre-MFMA
// lgkmcnt(0) at top of t-1, which precedes the end-of-(t-1) barrier.
// Granule swizzle both sides (verified involution): LDS granule g of row r
// holds global k-chunk g ^ ((r>>1)&3). 0 bank conflicts (R3/R5/R8).
__global__ __launch_bounds__(256, 2) void gemm_kernel(const f16* __restrict__ A16,
                                                      const f16* __restrict__ B16,
                                                      float* __restrict__ down) {
  __shared__ __align__(16) char sm[4][16384];   // per buf: A[128][32] | B[128][32] f16
  const int orig = blockIdx.x;                  // 4000 blocks = 8 * 500 (bijective)
  const int bid  = (orig & 7) * 500 + (orig >> 3);
  const int rt   = bid & 15;                    // 16 row tiles
  const int ct   = bid >> 4;                    // 250 col tiles
  const int r0   = rt * 128, c0 = ct * 128;
  const int tid  = threadIdx.x;
  const int lane = tid & 63;
  const int w    = tid >> 6;
  const int wr   = w >> 1, wc = w & 1;

  // staging: lane l of instr covers LDS bytes instr*1024 + l*16
  //   row = instr*16 + (l>>2); source k-granule = (l&3) ^ ((l>>3)&3)
  const int srow = lane >> 2;
  const int sel  = ((lane & 3) ^ ((lane >> 3) & 3)) * 8;   // f16 elems

  auto stage = [&](int buf, int t) {
    const int kbase = t * 32;
#pragma unroll
    for (int i = 0; i < 2; ++i) {
      int instr = w * 2 + i;                    // 8 instrs cover 128 rows
      gload_lds16(A16 + (size_t)(r0 + instr * 16 + srow) * 512 + kbase + sel,
                  &sm[buf][instr * 1024]);
    }
#pragma unroll
    for (int i = 0; i < 2; ++i) {
      int instr = w * 2 + i;
      gload_lds16(B16 + (size_t)(c0 + instr * 16 + srow) * 512 + kbase + sel,
                  &sm[buf][8192 + instr * 1024]);
    }
  };

  f32x4 acc[4][4] = {};

  // prologue: fill 3 ring slots (12 loads/wave); vmcnt(4) proves K0,K1 landed
  stage(0, 0);
  stage(1, 1);
  stage(2, 2);
  asm volatile("s_waitcnt vmcnt(4)" ::: "memory");
  __builtin_amdgcn_s_barrier();
  asm volatile("" ::: "memory");

  // swizzled read granule: kc = lane>>4, row bits 1-2 = (lane>>1)&3
  const int koff = (((lane >> 4) ^ ((lane >> 1) & 3)) * 16);
  const int arow = (wr * 64 + (lane & 15)) * 64;
  const int brow = (wc * 64 + (lane & 15)) * 64;

  f16x8 af[2][4], bf[2][4];

  // pre-loop prefetch: K0 fragments into set 0
#pragma unroll
  for (int mi = 0; mi < 4; ++mi)
    af[0][mi] = *reinterpret_cast<const f16x8*>(&sm[0][arow + mi * 1024 + koff]);
#pragma unroll
  for (int ni = 0; ni < 4; ++ni)
    bf[0][ni] = *reinterpret_cast<const f16x8*>(&sm[0][8192 + brow + ni * 1024 + koff]);

#pragma unroll
  for (int t = 0; t < 16; ++t) {
    const int s = t & 1, ns = s ^ 1;

    // frags for step t (issued during t-1) are in flight -> wait, then fence
    asm volatile("s_waitcnt lgkmcnt(0)" ::: "memory");
    __builtin_amdgcn_sched_barrier(0);

    // prefetch step t+1's fragments (slot proven landed at boundary t-1)
    if (t < 15) {
      const int nb = (t + 1) & 3;
#pragma unroll
      for (int mi = 0; mi < 4; ++mi)
        af[ns][mi] = *reinterpret_cast<const f16x8*>(&sm[nb][arow + mi * 1024 + koff]);
#pragma unroll
      for (int ni = 0; ni < 4; ++ni)
        bf[ns][ni] = *reinterpret_cast<const f16x8*>(&sm[nb][8192 + brow + ni * 1024 + koff]);
    }

    __builtin_amdgcn_s_setprio(1);
#pragma unroll
    for (int mi = 0; mi < 4; ++mi)
#pragma unroll
      for (int ni = 0; ni < 4; ++ni)
        acc[mi][ni] = __builtin_amdgcn_mfma_f32_16x16x32_f16(
            af[s][mi], bf[s][ni], acc[mi][ni], 0, 0, 0);
    __builtin_amdgcn_s_setprio(0);

    if (t + 3 < 16) stage((t + 3) & 3, t + 3);

    if (t < 15) {
      // boundary: prove K(t+2) (needed by prefetch during t+1).
      // in-flight: K(t+2) 4 + K(t+3) 4 -> vmcnt(4). At t=13 only K15's 4
      // remain -> vmcnt(0). t=14: nothing outstanding matters.
      if (t <= 12)      asm volatile("s_waitcnt vmcnt(4)" ::: "memory");
      else if (t == 13) asm volatile("s_waitcnt vmcnt(0)" ::: "memory");
      __builtin_amdgcn_s_barrier();
      asm volatile("" ::: "memory");
    }
  }

  // epilogue: exp + sum over this wave's 64 columns, then atomic into down[]
  // D layout: col = lane&15, row = (lane>>4)*4 + j  (m89-verified)
  const int rbase = r0 + wr * 64;
#pragma unroll
  for (int mi = 0; mi < 4; ++mi) {
    float s0 = 0.f, s1 = 0.f, s2 = 0.f, s3 = 0.f;
#pragma unroll
    for (int ni = 0; ni < 4; ++ni) {
      f32x4 v = acc[mi][ni];
      s0 += __expf(INV_TAU * v[0]);
      s1 += __expf(INV_TAU * v[1]);
      s2 += __expf(INV_TAU * v[2]);
      s3 += __expf(INV_TAU * v[3]);
    }
#pragma unroll
    for (int m = 1; m <= 8; m <<= 1) {
      s0 += __shfl_xor(s0, m);
      s1 += __shfl_xor(s1, m);
      s2 += __shfl_xor(s2, m);
      s3 += __shfl_xor(s3, m);
    }
    if ((lane & 15) == 0) {
      int row = rbase + mi * 16 + (lane >> 4) * 4;
      atomicAdd(&down[row + 0], s0);
      atomicAdd(&down[row + 1], s1);
      atomicAdd(&down[row + 2], s2);
      atomicAdd(&down[row + 3], s3);
    }
  }
}

// ---------------- kernel 4a: partial[r] += sum over one e-octant of EN.DE
__global__ void partial_kernel(const float* __restrict__ EN, const float* __restrict__ DE,
                               float* __restrict__ partial) {
  __shared__ float red[4][64];
  const int bk = blockIdx.x;
  const int r0 = (bk & 31) * 64;            // row group (b*512+l), 32 groups
  const int eo = (bk >> 5) * 64;            // e-octant base
  const int b  = r0 >> 9;
  const int l0 = r0 & 511;
  const int t  = threadIdx.x;
  const int ll = t & 63;
  const int g  = t >> 6;                    // 4 e-subchunks of 16
  float p = 0.f;
  const int ebase = eo + g * 16;
#pragma unroll 4
  for (int e = 0; e < 16; ++e) {
    size_t idx = (size_t)(b * 512 + ebase + e) * 512 + l0 + ll;
    p += EN[idx] * DE[idx];
  }
  red[g][ll] = p;
  __syncthreads();
  if (t < 64) {
    float s = red[0][t] + red[1][t] + red[2][t] + red[3][t];
    atomicAdd(&partial[r0 + t], s);
  }
}

// ---------------- kernel 4b: out = sum_r exp(partial[r]/tau) / down[r]
__global__ void finalize2_kernel(const float* __restrict__ partial,
                                 const float* __restrict__ down,
                                 float* __restrict__ out) {
  __shared__ float red[4];
  const int r = blockIdx.x * 256 + threadIdx.x;
  const int lane = threadIdx.x & 63;
  const int w = threadIdx.x >> 6;
  float val = __expf(INV_TAU * partial[r]) / down[r];
#pragma unroll
  for (int m = 1; m <= 32; m <<= 1) val += __shfl_xor(val, m);
  if (lane == 0) red[w] = val;
  __syncthreads();
  if (threadIdx.x == 0)
    atomicAdd(out, red[0] + red[1] + red[2] + red[3]);
}

extern "C" void kernel_launch(void* const* d_in, const int* in_sizes, int n_in,
                              void* d_out, int out_size, void* d_ws, size_t ws_size,
                              hipStream_t stream) {
  const float* EN = (const float*)d_in[0];
  const float* DE = (const float*)d_in[1];
  const float* M  = (const float*)d_in[2];

  // ws layout: down[2048] f32 | partial[2048] f32 | A16 [2048*512] f16 | B16 [32000*512] f16
  float* down    = (float*)d_ws;
  float* partial = (float*)((char*)d_ws + 8192);
  f16* A16 = (f16*)((char*)d_ws + 16384);
  f16* B16 = (f16*)((char*)d_ws + 16384 + (size_t)RDIM * EDIM * 2);
  const size_t need = 16384 + (size_t)RDIM * EDIM * 2 + (size_t)VDIM * EDIM * 2;

  hipMemsetAsync(d_out, 0, sizeof(float), stream);
  if (ws_size < need) return;
  hipMemsetAsync(d_ws, 0, 16384, stream);    // zero down + partial

  cvtA_kernel<<<dim3(8, 8, 4), 256, 0, stream>>>(DE, A16);
  cvtM_kernel<<<2048, 256, 0, stream>>>(M, B16);
  partial_kernel<<<256, 256, 0, stream>>>(EN, DE, partial);
  gemm_kernel<<<4000, 256, 0, stream>>>(A16, B16, down);
  finalize2_kernel<<<8, 256, 0, stream>>>(partial, down, (float*)d_out);
}

// Round 10
// 114.182 us; speedup vs baseline: 1.1078x; 1.1078x over previous
//
#include <hip/hip_runtime.h>

using f16   = _Float16;
using f16x4 = __attribute__((ext_vector_type(4))) _Float16;
using f16x8 = __attribute__((ext_vector_type(8))) _Float16;
using f32x4 = __attribute__((ext_vector_type(4))) float;

#define BDIM 4
#define EDIM 512
#define LDIM 512
#define VDIM 32000
#define RDIM 2048            // B*L
#define INV_TAU 0.1f

using gcvoid = const __attribute__((address_space(1))) void;
using lvoid  = __attribute__((address_space(3))) void;

__device__ __forceinline__ void gload_lds16(const void* g, void* l) {
  __builtin_amdgcn_global_load_lds((gcvoid*)g, (lvoid*)l, 16, 0, 0);
}

// ---------------- kernel 1: fused  DE->A16 transpose+convert  +  partial dot
// Per block (64e x 64l of one b): stage DE tile in LDS, write A16 transposed,
// and accumulate sum_e EN*DE per l-column -> atomicAdd into partial[b*512+l].
__global__ void cvtA_kernel(const float* __restrict__ DE, const float* __restrict__ EN,
                            f16* __restrict__ A16, float* __restrict__ partial) {
  __shared__ float tile[64][65];
  __shared__ float4 psum[16][16];           // [e-group][l4-group]
  const int b  = blockIdx.z;
  const int e0 = blockIdx.y * 64;
  const int l0 = blockIdx.x * 64;
  const int t  = threadIdx.x;
  float a0 = 0.f, a1 = 0.f, a2 = 0.f, a3 = 0.f;
#pragma unroll
  for (int i = 0; i < 4; ++i) {
    int idx = t + i * 256;                  // el = t>>4 + 16*i, l4 fixed per thread
    int el  = idx >> 4;
    int l4  = (idx & 15) * 4;
    size_t base = (size_t)(b * 512 + e0 + el) * 512 + l0 + l4;
    float4 v = *reinterpret_cast<const float4*>(DE + base);
    float4 u = *reinterpret_cast<const float4*>(EN + base);
    tile[el][l4 + 0] = v.x;
    tile[el][l4 + 1] = v.y;
    tile[el][l4 + 2] = v.z;
    tile[el][l4 + 3] = v.w;
    a0 += v.x * u.x; a1 += v.y * u.y; a2 += v.z * u.z; a3 += v.w * u.w;
  }
  psum[t >> 4][t & 15] = make_float4(a0, a1, a2, a3);
  __syncthreads();
#pragma unroll
  for (int i = 0; i < 4; ++i) {
    int idx = t + i * 256;
    int ll  = idx >> 4;
    int e4  = (idx & 15) * 4;
    f16x4 h;
    h[0] = (f16)tile[e4 + 0][ll];
    h[1] = (f16)tile[e4 + 1][ll];
    h[2] = (f16)tile[e4 + 2][ll];
    h[3] = (f16)tile[e4 + 3][ll];
    *reinterpret_cast<f16x4*>(A16 + (size_t)(b * 512 + l0 + ll) * 512 + e0 + e4) = h;
  }
  if (t < 64) {                             // column t: sum 16 e-groups
    const float* pcol = reinterpret_cast<const float*>(&psum[0][0]);
    float s = 0.f;
#pragma unroll
    for (int g = 0; g < 16; ++g) s += pcol[g * 64 + t];
    atomicAdd(&partial[(b << 9) + l0 + t], s);
  }
}

// ---------------- kernel 2: M [V,E] f32 -> B16 [V][E] f16 (stream convert, 16B stores)
__global__ void cvtM_kernel(const float* __restrict__ M, f16* __restrict__ B16) {
  const size_t N8 = (size_t)VDIM * EDIM / 8;
  const size_t stride = (size_t)gridDim.x * blockDim.x;
  for (size_t i = (size_t)blockIdx.x * blockDim.x + threadIdx.x; i < N8; i += stride) {
    float4 v0 = reinterpret_cast<const float4*>(M)[i * 2 + 0];
    float4 v1 = reinterpret_cast<const float4*>(M)[i * 2 + 1];
    f16x8 h = { (f16)v0.x, (f16)v0.y, (f16)v0.z, (f16)v0.w,
                (f16)v1.x, (f16)v1.y, (f16)v1.z, (f16)v1.w };
    reinterpret_cast<f16x8*>(B16)[i] = h;
  }
}

// ---------------- kernel 3: fused GEMM + exp + vocab-sum  (R8, byte-identical)
// 128x128 tile, BK=32, 16 K-tiles, 3-deep LDS ring (3 x 16KB = 48KB ->
// 3 blocks/CU). Counted vmcnt: stage K(t+2) during t (4 loads/wave); boundary
// s_waitcnt vmcnt(4) lgkmcnt(0) (t<=13), vmcnt(0) at t=14.
// Granule swizzle both sides (verified involution): LDS granule g of row r
// holds global k-chunk g ^ ((r>>1)&3). 0 bank conflicts (R3/R5/R8).
__global__ __launch_bounds__(256, 3) void gemm_kernel(const f16* __restrict__ A16,
                                                      const f16* __restrict__ B16,
                                                      float* __restrict__ down) {
  __shared__ __align__(16) char sm[3][16384];   // per buf: A[128][32] | B[128][32] f16
  const int orig = blockIdx.x;                  // 4000 blocks = 8 * 500 (bijective)
  const int bid  = (orig & 7) * 500 + (orig >> 3);
  const int rt   = bid & 15;                    // 16 row tiles
  const int ct   = bid >> 4;                    // 250 col tiles
  const int r0   = rt * 128, c0 = ct * 128;
  const int tid  = threadIdx.x;
  const int lane = tid & 63;
  const int w    = tid >> 6;
  const int wr   = w >> 1, wc = w & 1;

  const int srow = lane >> 2;
  const int sel  = ((lane & 3) ^ ((lane >> 3) & 3)) * 8;   // f16 elems

  auto stage = [&](int buf, int t) {
    const int kbase = t * 32;
#pragma unroll
    for (int i = 0; i < 2; ++i) {
      int instr = w * 2 + i;                    // 8 instrs cover 128 rows
      gload_lds16(A16 + (size_t)(r0 + instr * 16 + srow) * 512 + kbase + sel,
                  &sm[buf][instr * 1024]);
    }
#pragma unroll
    for (int i = 0; i < 2; ++i) {
      int instr = w * 2 + i;
      gload_lds16(B16 + (size_t)(c0 + instr * 16 + srow) * 512 + kbase + sel,
                  &sm[buf][8192 + instr * 1024]);
    }
  };

  f32x4 acc[4][4] = {};

  stage(0, 0);
  stage(1, 1);
  asm volatile("s_waitcnt vmcnt(4)" ::: "memory");
  __builtin_amdgcn_s_barrier();
  asm volatile("" ::: "memory");

  const int koff = (((lane >> 4) ^ ((lane >> 1) & 3)) * 16);
  const int arow = (wr * 64 + (lane & 15)) * 64;
  const int brow = (wc * 64 + (lane & 15)) * 64;

#pragma unroll
  for (int t = 0; t < 16; ++t) {
    const int cur = t % 3;
    f16x8 af[4], bf[4];
#pragma unroll
    for (int mi = 0; mi < 4; ++mi)
      af[mi] = *reinterpret_cast<const f16x8*>(&sm[cur][arow + mi * 1024 + koff]);
#pragma unroll
    for (int ni = 0; ni < 4; ++ni)
      bf[ni] = *reinterpret_cast<const f16x8*>(&sm[cur][8192 + brow + ni * 1024 + koff]);

    if (t + 2 < 16) stage((t + 2) % 3, t + 2);

    __builtin_amdgcn_s_setprio(1);
#pragma unroll
    for (int mi = 0; mi < 4; ++mi)
#pragma unroll
      for (int ni = 0; ni < 4; ++ni)
        acc[mi][ni] = __builtin_amdgcn_mfma_f32_16x16x32_f16(
            af[mi], bf[ni], acc[mi][ni], 0, 0, 0);
    __builtin_amdgcn_s_setprio(0);

    if (t < 15) {
      if (t <= 13) asm volatile("s_waitcnt vmcnt(4) lgkmcnt(0)" ::: "memory");
      else         asm volatile("s_waitcnt vmcnt(0) lgkmcnt(0)" ::: "memory");
      __builtin_amdgcn_s_barrier();
      asm volatile("" ::: "memory");
    }
  }

  // epilogue: exp + sum over this wave's 64 columns, then atomic into down[]
  const int rbase = r0 + wr * 64;
#pragma unroll
  for (int mi = 0; mi < 4; ++mi) {
    float s0 = 0.f, s1 = 0.f, s2 = 0.f, s3 = 0.f;
#pragma unroll
    for (int ni = 0; ni < 4; ++ni) {
      f32x4 v = acc[mi][ni];
      s0 += __expf(INV_TAU * v[0]);
      s1 += __expf(INV_TAU * v[1]);
      s2 += __expf(INV_TAU * v[2]);
      s3 += __expf(INV_TAU * v[3]);
    }
#pragma unroll
    for (int m = 1; m <= 8; m <<= 1) {
      s0 += __shfl_xor(s0, m);
      s1 += __shfl_xor(s1, m);
      s2 += __shfl_xor(s2, m);
      s3 += __shfl_xor(s3, m);
    }
    if ((lane & 15) == 0) {
      int row = rbase + mi * 16 + (lane >> 4) * 4;
      atomicAdd(&down[row + 0], s0);
      atomicAdd(&down[row + 1], s1);
      atomicAdd(&down[row + 2], s2);
      atomicAdd(&down[row + 3], s3);
    }
  }
}

// ---------------- kernel 4: out[0] = sum_r exp(partial[r]/tau) / down[r]
// single block, plain store (no atomic, no pre-zero of d_out needed)
__global__ void finalize2_kernel(const float* __restrict__ partial,
                                 const float* __restrict__ down,
                                 float* __restrict__ out) {
  __shared__ float red[4];
  const int t = threadIdx.x;
  const int lane = t & 63;
  const int w = t >> 6;
  float val = 0.f;
#pragma unroll
  for (int j = 0; j < 8; ++j) {
    int r = t + j * 256;
    val += __expf(INV_TAU * partial[r]) / down[r];
  }
#pragma unroll
  for (int m = 1; m <= 32; m <<= 1) val += __shfl_xor(val, m);
  if (lane == 0) red[w] = val;
  __syncthreads();
  if (t == 0) out[0] = red[0] + red[1] + red[2] + red[3];
}

extern "C" void kernel_launch(void* const* d_in, const int* in_sizes, int n_in,
                              void* d_out, int out_size, void* d_ws, size_t ws_size,
                              hipStream_t stream) {
  const float* EN = (const float*)d_in[0];
  const float* DE = (const float*)d_in[1];
  const float* M  = (const float*)d_in[2];

  // ws layout: down[2048] f32 | partial[2048] f32 | A16 [2048*512] f16 | B16 [32000*512] f16
  float* down    = (float*)d_ws;
  float* partial = (float*)((char*)d_ws + 8192);
  f16* A16 = (f16*)((char*)d_ws + 16384);
  f16* B16 = (f16*)((char*)d_ws + 16384 + (size_t)RDIM * EDIM * 2);
  const size_t need = 16384 + (size_t)RDIM * EDIM * 2 + (size_t)VDIM * EDIM * 2;

  if (ws_size < need) {                      // diagnosable fail: out = 0
    hipMemsetAsync(d_out, 0, sizeof(float), stream);
    return;
  }
  hipMemsetAsync(d_ws, 0, 16384, stream);    // zero down + partial

  cvtM_kernel<<<2048, 256, 0, stream>>>(M, B16);
  cvtA_kernel<<<dim3(8, 8, 4), 256, 0, stream>>>(DE, EN, A16, partial);
  gemm_kernel<<<4000, 256, 0, stream>>>(A16, B16, down);
  finalize2_kernel<<<1, 256, 0, stream>>>(partial, down, (float*)d_out);
}

// Round 11
// 111.737 us; speedup vs baseline: 1.1321x; 1.0219x over previous
//
#include <hip/hip_runtime.h>

using f16   = _Float16;
using f16x4 = __attribute__((ext_vector_type(4))) _Float16;
using f16x8 = __attribute__((ext_vector_type(8))) _Float16;
using f32x4 = __attribute__((ext_vector_type(4))) float;

#define BDIM 4
#define EDIM 512
#define LDIM 512
#define VDIM 32000
#define RDIM 2048            // B*L
#define INV_TAU 0.1f

using gcvoid = const __attribute__((address_space(1))) void;
using lvoid  = __attribute__((address_space(3))) void;

__device__ __forceinline__ void gload_lds16(const void* g, void* l) {
  __builtin_amdgcn_global_load_lds((gcvoid*)g, (lvoid*)l, 16, 0, 0);
}

// ---------------- kernel 1 (merged prep): one dispatch does
//   blocks [0,2048)    : M [V,E] f32 -> B16 f16 (stream convert, 16B stores)
//   blocks [2048,2080) : DE -> A16 transpose+convert + partial[r] = EN.DE (plain store)
//   block  2080        : zero down[2048]
// All blocks independent -> deterministic; replaces 2 kernels + 1 memset.
#define CVTM_BLOCKS 2048
__global__ void prep_kernel(const float* __restrict__ M, const float* __restrict__ DE,
                            const float* __restrict__ EN, f16* __restrict__ B16,
                            f16* __restrict__ A16, float* __restrict__ partial,
                            float* __restrict__ down) {
  const int bid = blockIdx.x;
  const int t   = threadIdx.x;

  if (bid < CVTM_BLOCKS) {
    // ---- cvtM part ----
    const size_t N8 = (size_t)VDIM * EDIM / 8;
    const size_t stride = (size_t)CVTM_BLOCKS * 256;
    for (size_t i = (size_t)bid * 256 + t; i < N8; i += stride) {
      float4 v0 = reinterpret_cast<const float4*>(M)[i * 2 + 0];
      float4 v1 = reinterpret_cast<const float4*>(M)[i * 2 + 1];
      f16x8 h = { (f16)v0.x, (f16)v0.y, (f16)v0.z, (f16)v0.w,
                  (f16)v1.x, (f16)v1.y, (f16)v1.z, (f16)v1.w };
      reinterpret_cast<f16x8*>(B16)[i] = h;
    }
    return;
  }

  if (bid == CVTM_BLOCKS + 32) {
    // ---- down-zero part ----
#pragma unroll
    for (int j = 0; j < 8; ++j) down[t + j * 256] = 0.f;
    return;
  }

  // ---- cvtA + partial part: one block per (b, l0) stripe, loops 8 e-tiles ----
  __shared__ float tile[64][65];
  __shared__ float4 psum[16][16];           // [e-group][l4-group]
  const int bid2 = bid - CVTM_BLOCKS;       // 0..31
  const int b  = bid2 >> 3;
  const int l0 = (bid2 & 7) * 64;
  float a0 = 0.f, a1 = 0.f, a2 = 0.f, a3 = 0.f;

  for (int e0 = 0; e0 < 512; e0 += 64) {
#pragma unroll
    for (int i = 0; i < 4; ++i) {
      int idx = t + i * 256;
      int el  = idx >> 4;
      int l4  = (idx & 15) * 4;
      size_t base = (size_t)(b * 512 + e0 + el) * 512 + l0 + l4;
      float4 v = *reinterpret_cast<const float4*>(DE + base);
      float4 u = *reinterpret_cast<const float4*>(EN + base);
      tile[el][l4 + 0] = v.x;
      tile[el][l4 + 1] = v.y;
      tile[el][l4 + 2] = v.z;
      tile[el][l4 + 3] = v.w;
      a0 += v.x * u.x; a1 += v.y * u.y; a2 += v.z * u.z; a3 += v.w * u.w;
    }
    __syncthreads();
#pragma unroll
    for (int i = 0; i < 4; ++i) {
      int idx = t + i * 256;
      int ll  = idx >> 4;
      int e4  = (idx & 15) * 4;
      f16x4 h;
      h[0] = (f16)tile[e4 + 0][ll];
      h[1] = (f16)tile[e4 + 1][ll];
      h[2] = (f16)tile[e4 + 2][ll];
      h[3] = (f16)tile[e4 + 3][ll];
      *reinterpret_cast<f16x4*>(A16 + (size_t)(b * 512 + l0 + ll) * 512 + e0 + e4) = h;
    }
    __syncthreads();                        // protect tile overwrite next iter
  }

  psum[t >> 4][t & 15] = make_float4(a0, a1, a2, a3);
  __syncthreads();
  if (t < 64) {                             // column t: sum 16 e-groups
    const float* pcol = reinterpret_cast<const float*>(&psum[0][0]);
    float s = 0.f;
#pragma unroll
    for (int g = 0; g < 16; ++g) s += pcol[g * 64 + t];
    partial[(b << 9) + l0 + t] = s;         // plain store (sole writer)
  }
}

// ---------------- kernel 2: fused GEMM + exp + vocab-sum  (R8/R10, byte-identical)
// 128x128 tile, BK=32, 16 K-tiles, 3-deep LDS ring (3 x 16KB = 48KB ->
// 3 blocks/CU). Counted vmcnt: stage K(t+2) during t (4 loads/wave); boundary
// s_waitcnt vmcnt(4) lgkmcnt(0) (t<=13), vmcnt(0) at t=14.
// Granule swizzle both sides (verified involution): LDS granule g of row r
// holds global k-chunk g ^ ((r>>1)&3). 0 bank conflicts (R3/R5/R8/R10).
__global__ __launch_bounds__(256, 3) void gemm_kernel(const f16* __restrict__ A16,
                                                      const f16* __restrict__ B16,
                                                      float* __restrict__ down) {
  __shared__ __align__(16) char sm[3][16384];   // per buf: A[128][32] | B[128][32] f16
  const int orig = blockIdx.x;                  // 4000 blocks = 8 * 500 (bijective)
  const int bid  = (orig & 7) * 500 + (orig >> 3);
  const int rt   = bid & 15;                    // 16 row tiles
  const int ct   = bid >> 4;                    // 250 col tiles
  const int r0   = rt * 128, c0 = ct * 128;
  const int tid  = threadIdx.x;
  const int lane = tid & 63;
  const int w    = tid >> 6;
  const int wr   = w >> 1, wc = w & 1;

  const int srow = lane >> 2;
  const int sel  = ((lane & 3) ^ ((lane >> 3) & 3)) * 8;   // f16 elems

  auto stage = [&](int buf, int t) {
    const int kbase = t * 32;
#pragma unroll
    for (int i = 0; i < 2; ++i) {
      int instr = w * 2 + i;                    // 8 instrs cover 128 rows
      gload_lds16(A16 + (size_t)(r0 + instr * 16 + srow) * 512 + kbase + sel,
                  &sm[buf][instr * 1024]);
    }
#pragma unroll
    for (int i = 0; i < 2; ++i) {
      int instr = w * 2 + i;
      gload_lds16(B16 + (size_t)(c0 + instr * 16 + srow) * 512 + kbase + sel,
                  &sm[buf][8192 + instr * 1024]);
    }
  };

  f32x4 acc[4][4] = {};

  stage(0, 0);
  stage(1, 1);
  asm volatile("s_waitcnt vmcnt(4)" ::: "memory");
  __builtin_amdgcn_s_barrier();
  asm volatile("" ::: "memory");

  const int koff = (((lane >> 4) ^ ((lane >> 1) & 3)) * 16);
  const int arow = (wr * 64 + (lane & 15)) * 64;
  const int brow = (wc * 64 + (lane & 15)) * 64;

#pragma unroll
  for (int t = 0; t < 16; ++t) {
    const int cur = t % 3;
    f16x8 af[4], bf[4];
#pragma unroll
    for (int mi = 0; mi < 4; ++mi)
      af[mi] = *reinterpret_cast<const f16x8*>(&sm[cur][arow + mi * 1024 + koff]);
#pragma unroll
    for (int ni = 0; ni < 4; ++ni)
      bf[ni] = *reinterpret_cast<const f16x8*>(&sm[cur][8192 + brow + ni * 1024 + koff]);

    if (t + 2 < 16) stage((t + 2) % 3, t + 2);

    __builtin_amdgcn_s_setprio(1);
#pragma unroll
    for (int mi = 0; mi < 4; ++mi)
#pragma unroll
      for (int ni = 0; ni < 4; ++ni)
        acc[mi][ni] = __builtin_amdgcn_mfma_f32_16x16x32_f16(
            af[mi], bf[ni], acc[mi][ni], 0, 0, 0);
    __builtin_amdgcn_s_setprio(0);

    if (t < 15) {
      if (t <= 13) asm volatile("s_waitcnt vmcnt(4) lgkmcnt(0)" ::: "memory");
      else         asm volatile("s_waitcnt vmcnt(0) lgkmcnt(0)" ::: "memory");
      __builtin_amdgcn_s_barrier();
      asm volatile("" ::: "memory");
    }
  }

  // epilogue: exp + sum over this wave's 64 columns, then atomic into down[]
  const int rbase = r0 + wr * 64;
#pragma unroll
  for (int mi = 0; mi < 4; ++mi) {
    float s0 = 0.f, s1 = 0.f, s2 = 0.f, s3 = 0.f;
#pragma unroll
    for (int ni = 0; ni < 4; ++ni) {
      f32x4 v = acc[mi][ni];
      s0 += __expf(INV_TAU * v[0]);
      s1 += __expf(INV_TAU * v[1]);
      s2 += __expf(INV_TAU * v[2]);
      s3 += __expf(INV_TAU * v[3]);
    }
#pragma unroll
    for (int m = 1; m <= 8; m <<= 1) {
      s0 += __shfl_xor(s0, m);
      s1 += __shfl_xor(s1, m);
      s2 += __shfl_xor(s2, m);
      s3 += __shfl_xor(s3, m);
    }
    if ((lane & 15) == 0) {
      int row = rbase + mi * 16 + (lane >> 4) * 4;
      atomicAdd(&down[row + 0], s0);
      atomicAdd(&down[row + 1], s1);
      atomicAdd(&down[row + 2], s2);
      atomicAdd(&down[row + 3], s3);
    }
  }
}

// ---------------- kernel 3: out[0] = sum_r exp(partial[r]/tau) / down[r]
// single block, plain store (no atomic, no pre-zero of d_out needed)
__global__ void finalize2_kernel(const float* __restrict__ partial,
                                 const float* __restrict__ down,
                                 float* __restrict__ out) {
  __shared__ float red[4];
  const int t = threadIdx.x;
  const int lane = t & 63;
  const int w = t >> 6;
  float val = 0.f;
#pragma unroll
  for (int j = 0; j < 8; ++j) {
    int r = t + j * 256;
    val += __expf(INV_TAU * partial[r]) / down[r];
  }
#pragma unroll
  for (int m = 1; m <= 32; m <<= 1) val += __shfl_xor(val, m);
  if (lane == 0) red[w] = val;
  __syncthreads();
  if (t == 0) out[0] = red[0] + red[1] + red[2] + red[3];
}

extern "C" void kernel_launch(void* const* d_in, const int* in_sizes, int n_in,
                              void* d_out, int out_size, void* d_ws, size_t ws_size,
                              hipStream_t stream) {
  const float* EN = (const float*)d_in[0];
  const float* DE = (const float*)d_in[1];
  const float* M  = (const float*)d_in[2];

  // ws layout: down[2048] f32 | partial[2048] f32 | A16 [2048*512] f16 | B16 [32000*512] f16
  float* down    = (float*)d_ws;
  float* partial = (float*)((char*)d_ws + 8192);
  f16* A16 = (f16*)((char*)d_ws + 16384);
  f16* B16 = (f16*)((char*)d_ws + 16384 + (size_t)RDIM * EDIM * 2);
  const size_t need = 16384 + (size_t)RDIM * EDIM * 2 + (size_t)VDIM * EDIM * 2;

  if (ws_size < need) {                      // diagnosable fail: out = 0
    hipMemsetAsync(d_out, 0, sizeof(float), stream);
    return;
  }

  prep_kernel<<<CVTM_BLOCKS + 33, 256, 0, stream>>>(M, DE, EN, B16, A16, partial, down);
  gemm_kernel<<<4000, 256, 0, stream>>>(A16, B16, down);
  finalize2_kernel<<<1, 256, 0, stream>>>(partial, down, (float*)d_out);
}

// Round 12
// 108.855 us; speedup vs baseline: 1.1620x; 1.0265x over previous
//
#include <hip/hip_runtime.h>

using f16   = _Float16;
using f16x4 = __attribute__((ext_vector_type(4))) _Float16;
using f16x8 = __attribute__((ext_vector_type(8))) _Float16;
using f32x4 = __attribute__((ext_vector_type(4))) float;

#define BDIM 4
#define EDIM 512
#define LDIM 512
#define VDIM 32000
#define RDIM 2048            // B*L
#define INV_TAU 0.1f

using gcvoid = const __attribute__((address_space(1))) void;
using lvoid  = __attribute__((address_space(3))) void;

__device__ __forceinline__ void gload_lds16(const void* g, void* l) {
  __builtin_amdgcn_global_load_lds((gcvoid*)g, (lvoid*)l, 16, 0, 0);
}

// ---------------- kernel 1 (merged prep): one dispatch does
//   blocks [0,2048)    : M [V,E] f32 -> B16 f16 (stream convert, 16B stores)
//   blocks [2048,2080) : DE -> A16 transpose+convert + partial[r] = EN.DE (plain store)
//   block  2080        : zero down[2048]
#define CVTM_BLOCKS 2048
__global__ void prep_kernel(const float* __restrict__ M, const float* __restrict__ DE,
                            const float* __restrict__ EN, f16* __restrict__ B16,
                            f16* __restrict__ A16, float* __restrict__ partial,
                            float* __restrict__ down) {
  const int bid = blockIdx.x;
  const int t   = threadIdx.x;

  if (bid < CVTM_BLOCKS) {
    const size_t N8 = (size_t)VDIM * EDIM / 8;
    const size_t stride = (size_t)CVTM_BLOCKS * 256;
    for (size_t i = (size_t)bid * 256 + t; i < N8; i += stride) {
      float4 v0 = reinterpret_cast<const float4*>(M)[i * 2 + 0];
      float4 v1 = reinterpret_cast<const float4*>(M)[i * 2 + 1];
      f16x8 h = { (f16)v0.x, (f16)v0.y, (f16)v0.z, (f16)v0.w,
                  (f16)v1.x, (f16)v1.y, (f16)v1.z, (f16)v1.w };
      reinterpret_cast<f16x8*>(B16)[i] = h;
    }
    return;
  }

  if (bid == CVTM_BLOCKS + 32) {
#pragma unroll
    for (int j = 0; j < 8; ++j) down[t + j * 256] = 0.f;
    return;
  }

  // ---- cvtA + partial: one block per (b, l0) stripe, loops 8 e-tiles ----
  __shared__ float tile[64][65];
  __shared__ float4 psum[16][16];           // [e-group][l4-group]
  const int bid2 = bid - CVTM_BLOCKS;       // 0..31
  const int b  = bid2 >> 3;
  const int l0 = (bid2 & 7) * 64;
  float a0 = 0.f, a1 = 0.f, a2 = 0.f, a3 = 0.f;

  for (int e0 = 0; e0 < 512; e0 += 64) {
#pragma unroll
    for (int i = 0; i < 4; ++i) {
      int idx = t + i * 256;
      int el  = idx >> 4;
      int l4  = (idx & 15) * 4;
      size_t base = (size_t)(b * 512 + e0 + el) * 512 + l0 + l4;
      float4 v = *reinterpret_cast<const float4*>(DE + base);
      float4 u = *reinterpret_cast<const float4*>(EN + base);
      tile[el][l4 + 0] = v.x;
      tile[el][l4 + 1] = v.y;
      tile[el][l4 + 2] = v.z;
      tile[el][l4 + 3] = v.w;
      a0 += v.x * u.x; a1 += v.y * u.y; a2 += v.z * u.z; a3 += v.w * u.w;
    }
    __syncthreads();
#pragma unroll
    for (int i = 0; i < 4; ++i) {
      int idx = t + i * 256;
      int ll  = idx >> 4;
      int e4  = (idx & 15) * 4;
      f16x4 h;
      h[0] = (f16)tile[e4 + 0][ll];
      h[1] = (f16)tile[e4 + 1][ll];
      h[2] = (f16)tile[e4 + 2][ll];
      h[3] = (f16)tile[e4 + 3][ll];
      *reinterpret_cast<f16x4*>(A16 + (size_t)(b * 512 + l0 + ll) * 512 + e0 + e4) = h;
    }
    __syncthreads();
  }

  psum[t >> 4][t & 15] = make_float4(a0, a1, a2, a3);
  __syncthreads();
  if (t < 64) {
    const float* pcol = reinterpret_cast<const float*>(&psum[0][0]);
    float s = 0.f;
#pragma unroll
    for (int g = 0; g < 16; ++g) s += pcol[g * 64 + t];
    partial[(b << 9) + l0 + t] = s;
  }
}

// ---------------- kernel 2: fused GEMM + exp + vocab-sum
// K-loop byte-identical to R8/R10/R11 (verified replay-stable, 0 conflicts).
// 128x128 tile, BK=32, 16 K-tiles, ring-3 LDS (48KB, 3 blk/CU), counted vmcnt.
// NEW (epilogue only, after the sync loop): cross-wc LDS pair-reduction so
// each down[] row gets ONE atomic per block instead of two -> halves the
// 64B write-through traffic (WRITE_SIZE 16->~8 MB) and atomic serialization.
__global__ __launch_bounds__(256, 3) void gemm_kernel(const f16* __restrict__ A16,
                                                      const f16* __restrict__ B16,
                                                      float* __restrict__ down) {
  __shared__ __align__(16) char sm[3][16384];   // per buf: A[128][32] | B[128][32] f16
  const int orig = blockIdx.x;                  // 4000 blocks = 8 * 500 (bijective)
  const int bid  = (orig & 7) * 500 + (orig >> 3);
  const int rt   = bid & 15;                    // 16 row tiles
  const int ct   = bid >> 4;                    // 250 col tiles
  const int r0   = rt * 128, c0 = ct * 128;
  const int tid  = threadIdx.x;
  const int lane = tid & 63;
  const int w    = tid >> 6;
  const int wr   = w >> 1, wc = w & 1;

  const int srow = lane >> 2;
  const int sel  = ((lane & 3) ^ ((lane >> 3) & 3)) * 8;   // f16 elems

  auto stage = [&](int buf, int t) {
    const int kbase = t * 32;
#pragma unroll
    for (int i = 0; i < 2; ++i) {
      int instr = w * 2 + i;                    // 8 instrs cover 128 rows
      gload_lds16(A16 + (size_t)(r0 + instr * 16 + srow) * 512 + kbase + sel,
                  &sm[buf][instr * 1024]);
    }
#pragma unroll
    for (int i = 0; i < 2; ++i) {
      int instr = w * 2 + i;
      gload_lds16(B16 + (size_t)(c0 + instr * 16 + srow) * 512 + kbase + sel,
                  &sm[buf][8192 + instr * 1024]);
    }
  };

  f32x4 acc[4][4] = {};

  stage(0, 0);
  stage(1, 1);
  asm volatile("s_waitcnt vmcnt(4)" ::: "memory");
  __builtin_amdgcn_s_barrier();
  asm volatile("" ::: "memory");

  const int koff = (((lane >> 4) ^ ((lane >> 1) & 3)) * 16);
  const int arow = (wr * 64 + (lane & 15)) * 64;
  const int brow = (wc * 64 + (lane & 15)) * 64;

#pragma unroll
  for (int t = 0; t < 16; ++t) {
    const int cur = t % 3;
    f16x8 af[4], bf[4];
#pragma unroll
    for (int mi = 0; mi < 4; ++mi)
      af[mi] = *reinterpret_cast<const f16x8*>(&sm[cur][arow + mi * 1024 + koff]);
#pragma unroll
    for (int ni = 0; ni < 4; ++ni)
      bf[ni] = *reinterpret_cast<const f16x8*>(&sm[cur][8192 + brow + ni * 1024 + koff]);

    if (t + 2 < 16) stage((t + 2) % 3, t + 2);

    __builtin_amdgcn_s_setprio(1);
#pragma unroll
    for (int mi = 0; mi < 4; ++mi)
#pragma unroll
      for (int ni = 0; ni < 4; ++ni)
        acc[mi][ni] = __builtin_amdgcn_mfma_f32_16x16x32_f16(
            af[mi], bf[ni], acc[mi][ni], 0, 0, 0);
    __builtin_amdgcn_s_setprio(0);

    if (t < 15) {
      if (t <= 13) asm volatile("s_waitcnt vmcnt(4) lgkmcnt(0)" ::: "memory");
      else         asm volatile("s_waitcnt vmcnt(0) lgkmcnt(0)" ::: "memory");
      __builtin_amdgcn_s_barrier();
      asm volatile("" ::: "memory");
    }
  }

  // ---- epilogue ----
  // exp + 16-col shuffle reduce as before; then wc==1 waves park sums in the
  // (now idle) ring slot 2, wc==0 waves add partner sums and do the atomics.
  // D layout: col = lane&15, row = (lane>>4)*4 + j  (m89-verified)
  __syncthreads();                              // all K-loop LDS reads complete
  float4* red = reinterpret_cast<float4*>(&sm[2][0]);   // 32 slots used
  float4 mysum[4];
#pragma unroll
  for (int mi = 0; mi < 4; ++mi) {
    float s0 = 0.f, s1 = 0.f, s2 = 0.f, s3 = 0.f;
#pragma unroll
    for (int ni = 0; ni < 4; ++ni) {
      f32x4 v = acc[mi][ni];
      s0 += __expf(INV_TAU * v[0]);
      s1 += __expf(INV_TAU * v[1]);
      s2 += __expf(INV_TAU * v[2]);
      s3 += __expf(INV_TAU * v[3]);
    }
#pragma unroll
    for (int m = 1; m <= 8; m <<= 1) {
      s0 += __shfl_xor(s0, m);
      s1 += __shfl_xor(s1, m);
      s2 += __shfl_xor(s2, m);
      s3 += __shfl_xor(s3, m);
    }
    mysum[mi] = make_float4(s0, s1, s2, s3);
    if (wc == 1 && (lane & 15) == 0)
      red[(wr * 4 + mi) * 4 + (lane >> 4)] = mysum[mi];
  }
  __syncthreads();
  if (wc == 0 && (lane & 15) == 0) {
    const int rbase = r0 + wr * 64;
#pragma unroll
    for (int mi = 0; mi < 4; ++mi) {
      float4 o = red[(wr * 4 + mi) * 4 + (lane >> 4)];
      int row = rbase + mi * 16 + (lane >> 4) * 4;
      atomicAdd(&down[row + 0], mysum[mi].x + o.x);
      atomicAdd(&down[row + 1], mysum[mi].y + o.y);
      atomicAdd(&down[row + 2], mysum[mi].z + o.z);
      atomicAdd(&down[row + 3], mysum[mi].w + o.w);
    }
  }
}

// ---------------- kernel 3: out[0] = sum_r exp(partial[r]/tau) / down[r]
__global__ void finalize2_kernel(const float* __restrict__ partial,
                                 const float* __restrict__ down,
                                 float* __restrict__ out) {
  __shared__ float red[4];
  const int t = threadIdx.x;
  const int lane = t & 63;
  const int w = t >> 6;
  float val = 0.f;
#pragma unroll
  for (int j = 0; j < 8; ++j) {
    int r = t + j * 256;
    val += __expf(INV_TAU * partial[r]) / down[r];
  }
#pragma unroll
  for (int m = 1; m <= 32; m <<= 1) val += __shfl_xor(val, m);
  if (lane == 0) red[w] = val;
  __syncthreads();
  if (t == 0) out[0] = red[0] + red[1] + red[2] + red[3];
}

extern "C" void kernel_launch(void* const* d_in, const int* in_sizes, int n_in,
                              void* d_out, int out_size, void* d_ws, size_t ws_size,
                              hipStream_t stream) {
  const float* EN = (const float*)d_in[0];
  const float* DE = (const float*)d_in[1];
  const float* M  = (const float*)d_in[2];

  // ws layout: down[2048] f32 | partial[2048] f32 | A16 [2048*512] f16 | B16 [32000*512] f16
  float* down    = (float*)d_ws;
  float* partial = (float*)((char*)d_ws + 8192);
  f16* A16 = (f16*)((char*)d_ws + 16384);
  f16* B16 = (f16*)((char*)d_ws + 16384 + (size_t)RDIM * EDIM * 2);
  const size_t need = 16384 + (size_t)RDIM * EDIM * 2 + (size_t)VDIM * EDIM * 2;

  if (ws_size < need) {                      // diagnosable fail: out = 0
    hipMemsetAsync(d_out, 0, sizeof(float), stream);
    return;
  }

  prep_kernel<<<CVTM_BLOCKS + 33, 256, 0, stream>>>(M, DE, EN, B16, A16, partial, down);
  gemm_kernel<<<4000, 256, 0, stream>>>(A16, B16, down);
  finalize2_kernel<<<1, 256, 0, stream>>>(partial, down, (float*)d_out);
}